// Round 1
// baseline (7129.237 us; speedup 1.0000x reference)
//
#include <hip/hip_runtime.h>

#define BATCH 131072
#define SEQT  20
#define NF    5
#define NH    32

// ---------- fast activations (v_exp_f32 / v_rcp_f32, ~1 ulp) ----------
__device__ __forceinline__ float fast_exp2(float x) {
#if __has_builtin(__builtin_amdgcn_exp2f)
    return __builtin_amdgcn_exp2f(x);
#else
    return exp2f(x);
#endif
}
__device__ __forceinline__ float fast_rcp(float x) {
#if __has_builtin(__builtin_amdgcn_rcpf)
    return __builtin_amdgcn_rcpf(x);
#else
    return 1.0f / x;
#endif
}
__device__ __forceinline__ float sigm(float x) {
    // 1/(1+e^-x) = 1/(1 + 2^(-x*log2e))
    return fast_rcp(1.0f + fast_exp2(x * -1.4426950408889634f));
}
__device__ __forceinline__ float tanhf_(float x) {
    // tanh(x) = 1 - 2/(e^(2x)+1); e^(2x) = 2^(x*2*log2e)
    return 1.0f - 2.0f * fast_rcp(1.0f + fast_exp2(x * 2.8853900817779268f));
}

// ---------- one LSTM time-step, PyTorch gate order i,f,g,o ----------
// Wih: [4*NH, I], Whh: [4*NH, NH]. All loops fully unrolled so h/c/hn
// stay in registers (static indexing only). Weight indices are
// wave-uniform -> compiler emits scalar (s_load) broadcasts.
template<int I>
__device__ __forceinline__ void lstm_step(
    const float* __restrict__ Wih, const float* __restrict__ Whh,
    const float* __restrict__ bih, const float* __restrict__ bhh,
    const float* __restrict__ xin, float* __restrict__ h, float* __restrict__ c)
{
    float hn[NH];
#pragma unroll
    for (int j = 0; j < NH; ++j) {
        float zi = bih[j]          + bhh[j];
        float zf = bih[NH + j]     + bhh[NH + j];
        float zg = bih[2 * NH + j] + bhh[2 * NH + j];
        float zo = bih[3 * NH + j] + bhh[3 * NH + j];
#pragma unroll
        for (int k = 0; k < I; ++k) {
            float xk = xin[k];
            zi = fmaf(xk, Wih[(j         ) * I + k], zi);
            zf = fmaf(xk, Wih[(NH     + j) * I + k], zf);
            zg = fmaf(xk, Wih[(2 * NH + j) * I + k], zg);
            zo = fmaf(xk, Wih[(3 * NH + j) * I + k], zo);
        }
#pragma unroll
        for (int k = 0; k < NH; ++k) {
            float hk = h[k];
            zi = fmaf(hk, Whh[(j         ) * NH + k], zi);
            zf = fmaf(hk, Whh[(NH     + j) * NH + k], zf);
            zg = fmaf(hk, Whh[(2 * NH + j) * NH + k], zg);
            zo = fmaf(hk, Whh[(3 * NH + j) * NH + k], zo);
        }
        float ig = sigm(zi);
        float fg = sigm(zf);
        float gg = tanhf_(zg);
        float og = sigm(zo);
        float cj = fmaf(fg, c[j], ig * gg);
        c[j]  = cj;
        hn[j] = og * tanhf_(cj);
    }
#pragma unroll
    for (int j = 0; j < NH; ++j) h[j] = hn[j];
}

__global__ void __launch_bounds__(256, 2) lstm_ae_fused(
    const float* __restrict__ x,
    const float* __restrict__ eWih0, const float* __restrict__ eWhh0,
    const float* __restrict__ ebih0, const float* __restrict__ ebhh0,
    const float* __restrict__ eWih1, const float* __restrict__ eWhh1,
    const float* __restrict__ ebih1, const float* __restrict__ ebhh1,
    const float* __restrict__ bnW,   const float* __restrict__ bnB,
    const float* __restrict__ exW,   const float* __restrict__ exB,
    const float* __restrict__ dWih0, const float* __restrict__ dWhh0,
    const float* __restrict__ dbih0, const float* __restrict__ dbhh0,
    const float* __restrict__ dWih1, const float* __restrict__ dWhh1,
    const float* __restrict__ dbih1, const float* __restrict__ dbhh1,
    const float* __restrict__ outW,  const float* __restrict__ outB,
    float* __restrict__ out)
{
    const int b = blockIdx.x * 256 + threadIdx.x;
    const float* __restrict__ xb = x + (size_t)b * (SEQT * NF);

    float h0[NH], c0[NH], h1[NH], c1[NH];
#pragma unroll
    for (int j = 0; j < NH; ++j) { h0[j] = 0.f; c0[j] = 0.f; h1[j] = 0.f; c1[j] = 0.f; }

    // ---------------- encoder ----------------
    for (int t = 0; t < SEQT; ++t) {
        float xt[NF];
#pragma unroll
        for (int f = 0; f < NF; ++f) xt[f] = xb[t * NF + f];
        lstm_step<NF>(eWih0, eWhh0, ebih0, ebhh0, xt, h0, c0);
        lstm_step<NH>(eWih1, eWhh1, ebih1, ebhh1, h0, h1, c1);
    }

    // ---------------- bottleneck MLPs ----------------
    float lat[16];
#pragma unroll
    for (int i = 0; i < 16; ++i) {
        float a = bnB[i];
#pragma unroll
        for (int k = 0; k < NH; ++k) a = fmaf(h1[k], bnW[i * NH + k], a);
        lat[i] = fmaxf(a, 0.0f);
    }
    float ex[NH];
#pragma unroll
    for (int i = 0; i < NH; ++i) {
        float a = exB[i];
#pragma unroll
        for (int k = 0; k < 16; ++k) a = fmaf(lat[k], exW[i * 16 + k], a);
        ex[i] = fmaxf(a, 0.0f);
    }

    // ---------------- decoder (input = ex, constant over t) ----------------
#pragma unroll
    for (int j = 0; j < NH; ++j) { h0[j] = 0.f; c0[j] = 0.f; h1[j] = 0.f; c1[j] = 0.f; }

    float* __restrict__ ob = out + (size_t)b * (SEQT * NF);
    for (int t = 0; t < SEQT; ++t) {
        lstm_step<NH>(dWih0, dWhh0, dbih0, dbhh0, ex, h0, c0);
        lstm_step<NH>(dWih1, dWhh1, dbih1, dbhh1, h0, h1, c1);
#pragma unroll
        for (int f = 0; f < NF; ++f) {
            float a = outB[f];
#pragma unroll
            for (int k = 0; k < NH; ++k) a = fmaf(h1[k], outW[f * NH + k], a);
            ob[t * NF + f] = a;
        }
    }
}

extern "C" void kernel_launch(void* const* d_in, const int* in_sizes, int n_in,
                              void* d_out, int out_size, void* d_ws, size_t ws_size,
                              hipStream_t stream)
{
    const float* x     = (const float*)d_in[0];
    const float* eWih0 = (const float*)d_in[1];
    const float* eWhh0 = (const float*)d_in[2];
    const float* ebih0 = (const float*)d_in[3];
    const float* ebhh0 = (const float*)d_in[4];
    const float* eWih1 = (const float*)d_in[5];
    const float* eWhh1 = (const float*)d_in[6];
    const float* ebih1 = (const float*)d_in[7];
    const float* ebhh1 = (const float*)d_in[8];
    const float* bnW   = (const float*)d_in[9];
    const float* bnB   = (const float*)d_in[10];
    const float* exW   = (const float*)d_in[11];
    const float* exB   = (const float*)d_in[12];
    const float* dWih0 = (const float*)d_in[13];
    const float* dWhh0 = (const float*)d_in[14];
    const float* dbih0 = (const float*)d_in[15];
    const float* dbhh0 = (const float*)d_in[16];
    const float* dWih1 = (const float*)d_in[17];
    const float* dWhh1 = (const float*)d_in[18];
    const float* dbih1 = (const float*)d_in[19];
    const float* dbhh1 = (const float*)d_in[20];
    const float* outW  = (const float*)d_in[21];
    const float* outB  = (const float*)d_in[22];

    dim3 grid(BATCH / 256), block(256);
    hipLaunchKernelGGL(lstm_ae_fused, grid, block, 0, stream,
                       x,
                       eWih0, eWhh0, ebih0, ebhh0,
                       eWih1, eWhh1, ebih1, ebhh1,
                       bnW, bnB, exW, exB,
                       dWih0, dWhh0, dbih0, dbhh0,
                       dWih1, dWhh1, dbih1, dbhh1,
                       outW, outB,
                       (float*)d_out);
}

// Round 2
// 528.912 us; speedup vs baseline: 13.4791x; 13.4791x over previous
//
#include <hip/hip_runtime.h>

typedef float f32x4 __attribute__((ext_vector_type(4)));
typedef short bf16x8 __attribute__((ext_vector_type(8)));

#define BATCH 131072
#define SEQT  20

// ---------- fast activations ----------
__device__ __forceinline__ float fexp2(float x){ return __builtin_amdgcn_exp2f(x); }
__device__ __forceinline__ float frcp (float x){ return __builtin_amdgcn_rcpf(x); }
__device__ __forceinline__ float sigm (float x){ return frcp(1.0f + fexp2(x * -1.4426950408889634f)); }
__device__ __forceinline__ float tanh_(float x){ return 1.0f - 2.0f*frcp(1.0f + fexp2(x * 2.8853900817779268f)); }

// ---------- bf16 helpers (RNE) ----------
__device__ __forceinline__ unsigned short f2bf(float f){
  unsigned u = __float_as_uint(f);
  return (unsigned short)((u + 0x7fffu + ((u>>16)&1u)) >> 16);
}
__device__ __forceinline__ float bf2f(unsigned short b){ return __uint_as_float(((unsigned)b)<<16); }
__device__ __forceinline__ unsigned pk2(float a, float b){ return (unsigned)f2bf(a) | ((unsigned)f2bf(b)<<16); }

__device__ __forceinline__ f32x4 MFMA(bf16x8 a, bf16x8 b, f32x4 c){
  return __builtin_amdgcn_mfma_f32_16x16x32_bf16(a, b, c, 0, 0, 0);
}
__device__ __forceinline__ bf16x8 zero8(){
  bf16x8 z;
#pragma unroll
  for (int e=0;e<8;++e) z[e]=0;
  return z;
}

// sigma column permutation: B-frag element e at lane-group kg holds hidden j = (e>>2)*16 + 4*kg + (e&3)
__device__ __forceinline__ int sigcol(int kg, int e){ return (e<4) ? (4*kg+e) : (16+4*kg+(e-4)); }

// A-frag loaders (row = global row of W; lane holds 8 K-elements)
__device__ __forceinline__ bf16x8 ldfragS(const float* __restrict__ W, int row, int kg){ // K=32, sigma cols
  bf16x8 f;
#pragma unroll
  for (int e=0;e<8;++e) f[e] = (short)f2bf(W[row*32 + sigcol(kg,e)]);
  return f;
}
__device__ __forceinline__ bf16x8 ldfragX(const float* __restrict__ W, int row, int kg){ // K=5 natural, zero-pad to 32
  bf16x8 f;
#pragma unroll
  for (int e=0;e<8;++e){
    f[e] = (short)((kg==0 && e<5) ? f2bf(W[row*5 + e]) : (short)0);
  }
  return f;
}
__device__ __forceinline__ bf16x8 ldfragE(const float* __restrict__ W, int row, int kg){ // K=16 (latent), sigma2: col=4kg+e for e<4
  bf16x8 f;
#pragma unroll
  for (int e=0;e<8;++e) f[e] = (short)((e<4) ? f2bf(W[row*16 + 4*kg + e]) : (short)0);
  return f;
}

// ---------- gate nonlinearity + state update + sigma-pack ----------
__device__ __forceinline__ void activate(const f32x4* acc, float* cs, bf16x8& ph, bf16x8& phr){
#pragma unroll
  for (int mm=0; mm<2; ++mm)
#pragma unroll
  for (int r=0; r<4; ++r){
    float zi = acc[0+mm][r];
    float zf = acc[2+mm][r];
    float zg = acc[4+mm][r];
    float zo = acc[6+mm][r];
    float ig = sigm(zi), fg = sigm(zf), gg = tanh_(zg), og = sigm(zo);
    const int e = mm*4 + r;
    float cn = fmaf(fg, cs[e], ig*gg);
    cs[e] = cn;
    float h = og * tanh_(cn);
    unsigned short hb = f2bf(h);
    ph[e]  = (short)hb;
    phr[e] = (short)f2bf(h - bf2f(hb));
  }
}

__global__ __launch_bounds__(256, 2) void lstm_ae_mfma(
    const float* __restrict__ x,
    const float* __restrict__ eWih0, const float* __restrict__ eWhh0,
    const float* __restrict__ ebih0, const float* __restrict__ ebhh0,
    const float* __restrict__ eWih1, const float* __restrict__ eWhh1,
    const float* __restrict__ ebih1, const float* __restrict__ ebhh1,
    const float* __restrict__ bnW,   const float* __restrict__ bnB,
    const float* __restrict__ exW,   const float* __restrict__ exB,
    const float* __restrict__ dWih0, const float* __restrict__ dWhh0,
    const float* __restrict__ dbih0, const float* __restrict__ dbhh0,
    const float* __restrict__ dWih1, const float* __restrict__ dWhh1,
    const float* __restrict__ dbih1, const float* __restrict__ dbhh1,
    const float* __restrict__ outW,  const float* __restrict__ outB,
    float* __restrict__ out)
{
  const int tid  = threadIdx.x;
  const int lane = tid & 63;
  const int w    = tid >> 6;      // wave id (0..3)
  const int cl   = lane & 15;     // batch col within wave / row-in-tile for A frags
  const int kg   = lane >> 4;     // k-group (0..3)

  // LDS: biases (576 f32) + x-frags (4 waves x 20 t x 16 col x 16B) + zero slot + out staging
  __shared__ __align__(16) float    sb[576];
  __shared__ __align__(16) unsigned sx[5124];
  __shared__ __align__(16) float    sout[6400];

  // ---- bias prep (bih+bhh summed) ----
  if (tid < 128){
    sb[      tid] = ebih0[tid] + ebhh0[tid];
    sb[128 + tid] = ebih1[tid] + ebhh1[tid];
    sb[256 + tid] = dbih0[tid] + dbhh0[tid];
    sb[384 + tid] = dbih1[tid] + dbhh1[tid];
  }
  if (tid < 16){
    sb[512 + tid] = (tid < 5) ? outB[tid] : 0.0f;
    sb[528 + tid] = bnB[tid];
  }
  if (tid < 32) sb[544 + tid] = exB[tid];
  if (tid < 4)  sx[5120 + tid] = 0u;

  // ---- x staging into B-frag layout (bf16, features at k=0..4, rest zero) ----
  const long blockb = (long)blockIdx.x * 64;
#pragma unroll
  for (int q=0; q<5; ++q){
    int s  = tid*5 + q;          // 0..1279 == (bb, t)
    int bb = s / 20;
    int t  = s - bb*20;
    const float* xp = x + (blockb + bb)*100 + t*5;
    float v0=xp[0], v1=xp[1], v2=xp[2], v3=xp[3], v4=xp[4];
    int base = (((bb>>4)*20 + t)*16 + (bb&15))*4;
    sx[base+0] = pk2(v0,v1);
    sx[base+1] = pk2(v2,v3);
    sx[base+2] = pk2(v4,0.0f);
    sx[base+3] = 0u;
  }
  __syncthreads();

  // ---- encoder weight fragments in registers ----
  bf16x8 WA[8], WB[8], WC[8], WD[8];   // Whh0, Wih0(x), Wih1, Whh1
#pragma unroll
  for (int m=0; m<8; ++m){
    WA[m] = ldfragS(eWhh0, m*16+cl, kg);
    WB[m] = ldfragX(eWih0, m*16+cl, kg);
    WC[m] = ldfragS(eWih1, m*16+cl, kg);
    WD[m] = ldfragS(eWhh1, m*16+cl, kg);
  }

  f32x4 acc[8];
  float cs0[8], cs1[8];
#pragma unroll
  for (int e=0;e<8;++e){ cs0[e]=0.f; cs1[e]=0.f; }
  bf16x8 ph0 = zero8(), ph0r = zero8(), ph1 = zero8(), ph1r = zero8();

  const unsigned xbase   = (kg==0) ? (unsigned)(w*1280 + cl*4) : 5120u;
  const unsigned xstride = (kg==0) ? 64u : 0u;

  // ================= encoder =================
  for (int t=0; t<SEQT; ++t){
    // enc layer 0: acc = bias0 + Whh0@(h0+res) + Wih0@x
#pragma unroll
    for (int m=0; m<8; ++m){
      f32x4 b = *(const f32x4*)&sb[0 + m*16 + kg*4];
      b = MFMA(WA[m], ph0r, b);
      b = MFMA(WA[m], ph0 , b);
      acc[m] = b;
    }
    bf16x8 xf = *(const bf16x8*)&sx[xbase + t*xstride];
#pragma unroll
    for (int m=0; m<8; ++m) acc[m] = MFMA(WB[m], xf, acc[m]);
    activate(acc, cs0, ph0, ph0r);

    // enc layer 1: acc = bias1 + Whh1@(h1+res) + Wih1@(h0+res)
#pragma unroll
    for (int m=0; m<8; ++m){
      f32x4 b = *(const f32x4*)&sb[128 + m*16 + kg*4];
      b = MFMA(WD[m], ph1r, b);
      b = MFMA(WD[m], ph1 , b);
      b = MFMA(WC[m], ph0r, b);
      b = MFMA(WC[m], ph0 , b);
      acc[m] = b;
    }
    activate(acc, cs1, ph1, ph1r);
  }

  // ================= bottleneck =================
  // latent = relu(bnW @ h1 + bnB): one 16x16 tile
  {
    bf16x8 WBN = ldfragS(bnW, cl, kg);
    f32x4 aL = *(const f32x4*)&sb[528 + kg*4];
    aL = MFMA(WBN, ph1r, aL);
    aL = MFMA(WBN, ph1 , aL);
    bf16x8 ltf = zero8(), ltr = zero8();
#pragma unroll
    for (int r=0; r<4; ++r){
      float v = fmaxf(aL[r], 0.0f);
      unsigned short hb = f2bf(v);
      ltf[r] = (short)hb;
      ltr[r] = (short)f2bf(v - bf2f(hb));
    }
    // ex = relu(exW @ latent + exB): two tiles (rows 0..31), K=16 (sigma2)
    f32x4 aE[2];
#pragma unroll
    for (int m=0; m<2; ++m){
      bf16x8 WE = ldfragE(exW, m*16+cl, kg);
      f32x4 b = *(const f32x4*)&sb[544 + m*16 + kg*4];
      b = MFMA(WE, ltr, b);
      b = MFMA(WE, ltf, b);
      aE[m] = b;
    }
    bf16x8 exf = zero8(), exr = zero8();
#pragma unroll
    for (int e=0; e<8; ++e){
      float v = fmaxf(aE[e>>2][e&3], 0.0f);
      unsigned short hb = f2bf(v);
      exf[e] = (short)hb;
      exr[e] = (short)f2bf(v - bf2f(hb));
    }
    // dec0 constant pre-activation: dpre = dbias0 + dWih0 @ ex  (held in regs)
#pragma unroll
    for (int m=0; m<8; ++m){
      bf16x8 wm = ldfragS(dWih0, m*16+cl, kg);
      f32x4 b = *(const f32x4*)&sb[256 + m*16 + kg*4];
      b = MFMA(wm, exr, b);
      b = MFMA(wm, exf, b);
      acc[m] = b;            // temporarily park dpre in acc
    }
  }
  f32x4 dpre[8];
#pragma unroll
  for (int m=0; m<8; ++m) dpre[m] = acc[m];

  // ---- decoder weights (reuse register arrays) ----
#pragma unroll
  for (int m=0; m<8; ++m){
    WA[m] = ldfragS(dWhh0, m*16+cl, kg);
    WC[m] = ldfragS(dWih1, m*16+cl, kg);
    WD[m] = ldfragS(dWhh1, m*16+cl, kg);
  }
  bf16x8 WO = zero8();
  if (cl < 5) WO = ldfragS(outW, cl, kg);
  const f32x4 obias = *(const f32x4*)&sb[512 + kg*4];

  // reset state
#pragma unroll
  for (int e=0;e<8;++e){ cs0[e]=0.f; cs1[e]=0.f; }
  ph0 = zero8(); ph0r = zero8(); ph1 = zero8(); ph1r = zero8();

  const int obase = w*1600 + cl*100;

  // ================= decoder =================
  for (int t=0; t<SEQT; ++t){
    // dec layer 0: acc = dpre + Whh0d@(h0+res)
#pragma unroll
    for (int m=0; m<8; ++m){
      f32x4 b = dpre[m];
      b = MFMA(WA[m], ph0r, b);
      b = MFMA(WA[m], ph0 , b);
      acc[m] = b;
    }
    activate(acc, cs0, ph0, ph0r);

    // dec layer 1
#pragma unroll
    for (int m=0; m<8; ++m){
      f32x4 b = *(const f32x4*)&sb[384 + m*16 + kg*4];
      b = MFMA(WD[m], ph1r, b);
      b = MFMA(WD[m], ph1 , b);
      b = MFMA(WC[m], ph0r, b);
      b = MFMA(WC[m], ph0 , b);
      acc[m] = b;
    }
    activate(acc, cs1, ph1, ph1r);

    // output projection (one padded tile, rows 0..4 live)
    f32x4 o = obias;
    o = MFMA(WO, ph1r, o);
    o = MFMA(WO, ph1 , o);
#pragma unroll
    for (int r=0; r<4; ++r){
      int f = 4*kg + r;
      if (f < 5) sout[obase + t*5 + f] = o[r];
    }
  }

  // ---- coalesced flush of staged outputs ----
  __syncthreads();
  float* __restrict__ ob = out + blockb*100;
#pragma unroll
  for (int q=0; q<25; ++q) ob[q*256 + tid] = sout[q*256 + tid];
}

extern "C" void kernel_launch(void* const* d_in, const int* in_sizes, int n_in,
                              void* d_out, int out_size, void* d_ws, size_t ws_size,
                              hipStream_t stream)
{
  const float* x     = (const float*)d_in[0];
  const float* eWih0 = (const float*)d_in[1];
  const float* eWhh0 = (const float*)d_in[2];
  const float* ebih0 = (const float*)d_in[3];
  const float* ebhh0 = (const float*)d_in[4];
  const float* eWih1 = (const float*)d_in[5];
  const float* eWhh1 = (const float*)d_in[6];
  const float* ebih1 = (const float*)d_in[7];
  const float* ebhh1 = (const float*)d_in[8];
  const float* bnW   = (const float*)d_in[9];
  const float* bnB   = (const float*)d_in[10];
  const float* exW   = (const float*)d_in[11];
  const float* exB   = (const float*)d_in[12];
  const float* dWih0 = (const float*)d_in[13];
  const float* dWhh0 = (const float*)d_in[14];
  const float* dbih0 = (const float*)d_in[15];
  const float* dbhh0 = (const float*)d_in[16];
  const float* dWih1 = (const float*)d_in[17];
  const float* dWhh1 = (const float*)d_in[18];
  const float* dbih1 = (const float*)d_in[19];
  const float* dbhh1 = (const float*)d_in[20];
  const float* outW  = (const float*)d_in[21];
  const float* outB  = (const float*)d_in[22];

  dim3 grid(BATCH / 64), block(256);
  hipLaunchKernelGGL(lstm_ae_mfma, grid, block, 0, stream,
                     x,
                     eWih0, eWhh0, ebih0, ebhh0,
                     eWih1, eWhh1, ebih1, ebhh1,
                     bnW, bnB, exW, exB,
                     dWih0, dWhh0, dbih0, dbhh0,
                     dWih1, dWhh1, dbih1, dbhh1,
                     outW, outB,
                     (float*)d_out);
}